// Round 3
// baseline (848.063 us; speedup 1.0000x reference)
//
#include <hip/hip_runtime.h>
#include <hip/hip_fp16.h>

#define E_EDGES 320000
#define NF 20

typedef float v4 __attribute__((ext_vector_type(4)));
typedef float v2f __attribute__((ext_vector_type(2)));

#if defined(__has_builtin)
# if __has_builtin(__builtin_elementwise_fma)
#  define EWFMA(a,b,c) __builtin_elementwise_fma((a),(b),(c))
# endif
#endif
#ifndef EWFMA
# define EWFMA(a,b,c) ((a)*(b)+(c))
#endif
#if defined(__has_builtin)
# if __has_builtin(__builtin_elementwise_max)
#  define EWMAX(a,b) __builtin_elementwise_max((a),(b))
#  define EWMIN(a,b) __builtin_elementwise_min((a),(b))
# endif
#endif

#if defined(__has_builtin)
# if __has_builtin(__builtin_amdgcn_exp2f)
#  define EX2F(x) __builtin_amdgcn_exp2f(x)
# endif
#endif
#ifndef EX2F
# define EX2F(x) exp2f(x)
#endif

#define LOG2E_F 1.4426950408889634f
#define SELU_SCALE 1.0507009873554805f
#define SELU_ALPHA 1.6732632423543772f
#define SELU_KA (SELU_SCALE * SELU_ALPHA)             /* scale*alpha */
#define SELU_SC2 (SELU_SCALE / LOG2E_F)               /* scale / log2e */

__device__ __forceinline__ v4 bc4(float s) { return (v4){s, s, s, s}; }
__device__ __forceinline__ v4 v4z() { return (v4){0.f, 0.f, 0.f, 0.f}; }

// DPP quad_perm helpers (VALU cross-lane, no LDS pipe)
#define DPP_XOR1 0xB1   /* quad_perm [1,0,3,2] */
#define DPP_XOR2 0x4E   /* quad_perm [2,3,0,1] */
template<int CTRL>
__device__ __forceinline__ float dppf(float x) {
    return __builtin_bit_cast(float,
        __builtin_amdgcn_update_dpp(0, __builtin_bit_cast(int, x), CTRL, 0xF, 0xF, true));
}
template<int CTRL>
__device__ __forceinline__ v4 dpp4(v4 x) {
    v4 r;
    r.x = dppf<CTRL>(x.x); r.y = dppf<CTRL>(x.y);
    r.z = dppf<CTRL>(x.z); r.w = dppf<CTRL>(x.w);
    return r;
}

__device__ __forceinline__ float selu_f(float x) {
    const float scale = SELU_SCALE;
    const float alpha = SELU_ALPHA;
    float p = fmaxf(x, 0.f);
    float m = fminf(x, 0.f);
    float e = __expf(m);
    return fmaf(scale, p, scale * alpha * (e - 1.f));
}
__device__ __forceinline__ float sigmoid_f(float x) {
    return 1.f / (1.f + __expf(-x));
}
// packed selu (used by readout only)
__device__ __forceinline__ v4 selu4(v4 x) {
    const float scale = SELU_SCALE;
    const float ka = SELU_KA;
#ifdef EWMAX
    v4 p = EWMAX(x, v4z());
    v4 m = EWMIN(x, v4z());
#else
    v4 p = {fmaxf(x.x,0.f), fmaxf(x.y,0.f), fmaxf(x.z,0.f), fmaxf(x.w,0.f)};
    v4 m = {fminf(x.x,0.f), fminf(x.y,0.f), fminf(x.z,0.f), fminf(x.w,0.f)};
#endif
    v4 e = {__expf(m.x), __expf(m.y), __expf(m.z), __expf(m.w)};
    return EWFMA(bc4(scale), p, EWFMA(bc4(ka), e, bc4(-ka)));
}

__device__ __forceinline__ float hsum4(v4 x) {
    v2f lo = __builtin_shufflevector(x, x, 0, 1);
    v2f hi = __builtin_shufflevector(x, x, 2, 3);
    v2f h = lo + hi;
    return h.x + h.y;
}

// one LDS row read serves BOTH edges, vertical pk-fma then horizontal reduce
__device__ __forceinline__ void dot20_dualv(const v4* __restrict__ w,
    v4 a0, v4 a1, v4 a2, v4 a3, v4 a4,
    v4 b0, v4 b1, v4 b2, v4 b3, v4 b4,
    float& r0, float& r1)
{
    v4 w0 = w[0], w1 = w[1], w2 = w[2], w3 = w[3], w4 = w[4];
    v4 xa = a0 * w0;
    xa = EWFMA(a1, w1, xa); xa = EWFMA(a2, w2, xa);
    xa = EWFMA(a3, w3, xa); xa = EWFMA(a4, w4, xa);
    v4 xb = b0 * w0;
    xb = EWFMA(b1, w1, xb); xb = EWFMA(b2, w2, xb);
    xb = EWFMA(b3, w3, xb); xb = EWFMA(b4, w4, xb);
    r0 = hsum4(xa);
    r1 = hsum4(xb);
}
__device__ __forceinline__ void h8_to_v4x2(uint4 r, v4& lo, v4& hi) {
    float2 fa = __half22float2(__builtin_bit_cast(__half2, r.x));
    float2 fb = __half22float2(__builtin_bit_cast(__half2, r.y));
    float2 fc = __half22float2(__builtin_bit_cast(__half2, r.z));
    float2 fd = __half22float2(__builtin_bit_cast(__half2, r.w));
    lo = (v4){fa.x, fa.y, fb.x, fb.y};
    hi = (v4){fc.x, fc.y, fd.x, fd.y};
}
__device__ __forceinline__ uint4 f8_to_h8(v4 lo, v4 hi) {
    uint4 r;
    r.x = __builtin_bit_cast(unsigned, __floats2half2_rn(lo.x, lo.y));
    r.y = __builtin_bit_cast(unsigned, __floats2half2_rn(lo.z, lo.w));
    r.z = __builtin_bit_cast(unsigned, __floats2half2_rn(hi.x, hi.y));
    r.w = __builtin_bit_cast(unsigned, __floats2half2_rn(hi.z, hi.w));
    return r;
}

#define FOR20(X) \
  X(0, v0.x) X(1, v0.y) X(2, v0.z) X(3, v0.w) \
  X(4, v1.x) X(5, v1.y) X(6, v1.z) X(7, v1.w) \
  X(8, v2.x) X(9, v2.y) X(10, v2.z) X(11, v2.w) \
  X(12, v3.x) X(13, v3.y) X(14, v3.z) X(15, v3.w) \
  X(16, v4v.x) X(17, v4v.y) X(18, v4v.z) X(19, v4v.w)

#define FOR20_2(X) \
  X(0, va0.x, vb0.x) X(1, va0.y, vb0.y) X(2, va0.z, vb0.z) X(3, va0.w, vb0.w) \
  X(4, va1.x, vb1.x) X(5, va1.y, vb1.y) X(6, va1.z, vb1.z) X(7, va1.w, vb1.w) \
  X(8, va2.x, vb2.x) X(9, va2.y, vb2.y) X(10, va2.z, vb2.z) X(11, va2.w, vb2.w) \
  X(12, va3.x, vb3.x) X(13, va3.y, vb3.y) X(14, va3.z, vb3.z) X(15, va3.w, vb3.w) \
  X(16, va4.x, vb4.x) X(17, va4.y, vb4.y) X(18, va4.z, vb4.z) X(19, va4.w, vb4.w)

#define FOR8S2(X) \
  X(0, sa0.x, sb0.x) X(1, sa0.y, sb0.y) X(2, sa0.z, sb0.z) X(3, sa0.w, sb0.w) \
  X(4, sa1.x, sb1.x) X(5, sa1.y, sb1.y) X(6, sa1.z, sb1.z) X(7, sa1.w, sb1.w)

// B[e][o] = (sum_f h[e][f] * W1[20+f][o] + b1[o]) * log2e, fp16 output.
__global__ void __launch_bounds__(256) kernel_B0(
    const float* __restrict__ h, const float* __restrict__ W1,
    const float* __restrict__ b1, __half* __restrict__ B)
{
    __shared__ __align__(16) float sw[640];
    __shared__ __align__(16) float sbias[32];
    for (int i = threadIdx.x; i < 640; i += 256) sw[i] = W1[640 + i] * LOG2E_F;
    if (threadIdx.x < 32) sbias[threadIdx.x] = b1[threadIdx.x] * LOG2E_F;
    __syncthreads();
    int e = blockIdx.x * 256 + threadIdx.x;
    const v4* hp = reinterpret_cast<const v4*>(h + (size_t)e * NF);
    v4 v0 = hp[0], v1 = hp[1], v2 = hp[2], v3 = hp[3], v4v = hp[4];
    const v4* bi = reinterpret_cast<const v4*>(sbias);
    v4 c0 = bi[0], c1 = bi[1], c2 = bi[2], c3 = bi[3],
       c4 = bi[4], c5 = bi[5], c6 = bi[6], c7 = bi[7];
    #define BSTEP(f, hf) { v4 t_ = bc4(hf); const v4* w_ = (const v4*)&sw[(f)*32]; \
        c0 = EWFMA(t_, w_[0], c0); c1 = EWFMA(t_, w_[1], c1); \
        c2 = EWFMA(t_, w_[2], c2); c3 = EWFMA(t_, w_[3], c3); \
        c4 = EWFMA(t_, w_[4], c4); c5 = EWFMA(t_, w_[5], c5); \
        c6 = EWFMA(t_, w_[6], c6); c7 = EWFMA(t_, w_[7], c7); }
    FOR20(BSTEP)
    #undef BSTEP
    uint4* Bp = reinterpret_cast<uint4*>(B + (size_t)e * 32);
    Bp[0] = f8_to_h8(c0, c1); Bp[1] = f8_to_h8(c2, c3);
    Bp[2] = f8_to_h8(c4, c5); Bp[3] = f8_to_h8(c6, c7);
}

// One step. 4 lanes/quad, 2 edges/thread, fp16 B gather (log2e-scaled),
// rolled GRU, DPP quad exchanges. WRITEB emits next step's B tile.
template<bool WRITEB>
__global__ void __launch_bounds__(256) kernel_stepT(
    const float* __restrict__ h_in, float* __restrict__ h_out,
    const __half* __restrict__ Br, const int* __restrict__ dst,
    const float* __restrict__ W1, const float* __restrict__ b1,
    const float* __restrict__ W2, const float* __restrict__ b2,
    const float* __restrict__ Wih, const float* __restrict__ Whh,
    const float* __restrict__ bih, const float* __restrict__ bhh,
    __half* __restrict__ Bw)
{
    __shared__ __align__(16) float sW1[640];   // rows 0-19 of msg_W1 (20,32), *log2e
    __shared__ __align__(16) float sW1h[640];  // rows 20-39 of msg_W1, *log2e (B-fuse)
    __shared__ __align__(16) float sb1h[32];   // b1 * log2e (B-fuse)
    __shared__ __align__(16) float sW2[640];   // (32,20)
    __shared__ __align__(16) float sb2v[20];
    __shared__ __align__(16) float sCorr[20];  // 16*(b2 - KA*colsum(W2))
    __shared__ __align__(16) float sWih[1200]; // (60,20)
    __shared__ __align__(16) float sWhh[1200];
    __shared__ float sbih[60];
    __shared__ float sbhh[60];
    for (int i = threadIdx.x; i < 640; i += 256) {
        sW1[i] = W1[i] * LOG2E_F;
        sW2[i] = W2[i];
        if (WRITEB) sW1h[i] = W1[640 + i] * LOG2E_F;
    }
    for (int i = threadIdx.x; i < 1200; i += 256) { sWih[i] = Wih[i]; sWhh[i] = Whh[i]; }
    if (threadIdx.x < 20) sb2v[threadIdx.x] = b2[threadIdx.x];
    else if (threadIdx.x >= 64 && threadIdx.x < 124) sbih[threadIdx.x - 64] = bih[threadIdx.x - 64];
    else if (threadIdx.x >= 128 && threadIdx.x < 188) sbhh[threadIdx.x - 128] = bhh[threadIdx.x - 128];
    else if (WRITEB && threadIdx.x >= 192 && threadIdx.x < 224)
        sb1h[threadIdx.x - 192] = b1[threadIdx.x - 192] * LOG2E_F;
    __syncthreads();
    if (threadIdx.x < 20) {
        float s = 0.f;
        #pragma unroll
        for (int o = 0; o < 32; o++) s += sW2[o * 20 + threadIdx.x];
        sCorr[threadIdx.x] = 16.f * (sb2v[threadIdx.x] - SELU_KA * s);
    }
    __syncthreads();

    int t = blockIdx.x * 256 + threadIdx.x;
    int p = t >> 2;
    int q = t & 3;
    int ob = q * 8;
    int e0 = p * 2, e1 = p * 2 + 1;

    int2 dd = *reinterpret_cast<const int2*>(dst + e0);
    int d0 = dd.x, d1 = dd.y;

    const v4* hp0 = reinterpret_cast<const v4*>(h_in + (size_t)e0 * NF);
    const v4* hp1 = reinterpret_cast<const v4*>(h_in + (size_t)e1 * NF);
    v4 va0 = hp0[0], va1 = hp0[1], va2 = hp0[2], va3 = hp0[3], va4 = hp0[4];
    v4 vb0 = hp1[0], vb1 = hp1[1], vb2 = hp1[2], vb3 = hp1[3], vb4 = hp1[4];

    // A' slices for both edges (already log2e-scaled via sW1 staging)
    v4 aa0 = v4z(), aa1 = v4z(), ab0 = v4z(), ab1 = v4z();
    #define ASTEP2(f, h0, h1) { const v4* w_ = (const v4*)&sW1[(f)*32 + ob]; \
        v4 w0_ = w_[0], w1_ = w_[1]; \
        v4 t0_ = bc4(h0), t1_ = bc4(h1); \
        aa0 = EWFMA(t0_, w0_, aa0); aa1 = EWFMA(t0_, w1_, aa1); \
        ab0 = EWFMA(t1_, w0_, ab0); ab1 = EWFMA(t1_, w1_, ab1); }
    FOR20_2(ASTEP2)
    #undef ASTEP2

    // gather 16 fp16 rows per edge; folded selu accumulate
    const uint4* Bp0 = reinterpret_cast<const uint4*>(Br) + (size_t)d0 * 64 + q;
    const uint4* Bp1 = reinterpret_cast<const uint4*>(Br) + (size_t)d1 * 64 + q;
    v4 sa0 = v4z(), sa1 = v4z(), sb0 = v4z(), sb1 = v4z();
    {
        v4 kav = bc4(SELU_KA), scv = bc4(SELU_SC2), z4 = v4z();
        #define SELUACC(s_, a_, b_) { v4 x_ = (a_) + (b_); \
            v4 p_ = EWMAX(x_, z4); v4 m_ = EWMIN(x_, z4); \
            v4 e_ = {EX2F(m_.x), EX2F(m_.y), EX2F(m_.z), EX2F(m_.w)}; \
            s_ = EWFMA(kav, e_, s_); s_ = EWFMA(scv, p_, s_); }
        #pragma unroll 4
        for (int k = 0; k < 16; k++) {
            uint4 rA = Bp0[k * 4];
            uint4 rB = Bp1[k * 4];
            v4 loA, hiA, loB, hiB;
            h8_to_v4x2(rA, loA, hiA);
            h8_to_v4x2(rB, loB, hiB);
            SELUACC(sa0, aa0, loA);
            SELUACC(sa1, aa1, hiA);
            SELUACC(sb0, ab0, loB);
            SELUACC(sb1, ab1, hiB);
        }
        #undef SELUACC
    }

    // partial agg (shared W2 rows, pk-fma)
    v4 ga0 = v4z(), ga1 = v4z(), ga2 = v4z(), ga3 = v4z(), ga4 = v4z();
    v4 gb0 = v4z(), gb1 = v4z(), gb2 = v4z(), gb3 = v4z(), gb4 = v4z();
    #define AGGS2(j, c0_, c1_) { const v4* w_ = (const v4*)&sW2[(ob + (j)) * 20]; \
        v4 w0_ = w_[0], w1_ = w_[1], w2_ = w_[2], w3_ = w_[3], w4_ = w_[4]; \
        v4 u_ = bc4(c0_), vv_ = bc4(c1_); \
        ga0 = EWFMA(u_, w0_, ga0); ga1 = EWFMA(u_, w1_, ga1); ga2 = EWFMA(u_, w2_, ga2); \
        ga3 = EWFMA(u_, w3_, ga3); ga4 = EWFMA(u_, w4_, ga4); \
        gb0 = EWFMA(vv_, w0_, gb0); gb1 = EWFMA(vv_, w1_, gb1); gb2 = EWFMA(vv_, w2_, gb2); \
        gb3 = EWFMA(vv_, w3_, gb3); gb4 = EWFMA(vv_, w4_, gb4); }
    FOR8S2(AGGS2)
    #undef AGGS2

    // quad butterfly via DPP (VALU only)
    #define BFLY(CTRL) { \
        ga0 = ga0 + dpp4<CTRL>(ga0); ga1 = ga1 + dpp4<CTRL>(ga1); \
        ga2 = ga2 + dpp4<CTRL>(ga2); ga3 = ga3 + dpp4<CTRL>(ga3); \
        ga4 = ga4 + dpp4<CTRL>(ga4); \
        gb0 = gb0 + dpp4<CTRL>(gb0); gb1 = gb1 + dpp4<CTRL>(gb1); \
        gb2 = gb2 + dpp4<CTRL>(gb2); gb3 = gb3 + dpp4<CTRL>(gb3); \
        gb4 = gb4 + dpp4<CTRL>(gb4); }
    BFLY(DPP_XOR1)
    BFLY(DPP_XOR2)
    #undef BFLY

    {
        const v4* cp = reinterpret_cast<const v4*>(sCorr);
        v4 c0 = cp[0], c1 = cp[1], c2 = cp[2], c3 = cp[3], c4 = cp[4];
        ga0 = ga0 + c0; ga1 = ga1 + c1; ga2 = ga2 + c2; ga3 = ga3 + c3; ga4 = ga4 + c4;
        gb0 = gb0 + c0; gb1 = gb1 + c1; gb2 = gb2 + c2; gb3 = gb3 + c3; gb4 = gb4 + c4;
    }

    // next-step B accumulators (8 output chans per lane per edge)
    v4 ba0, ba1, bb0, bb1;
    if (WRITEB) {
        const v4* b1p = reinterpret_cast<const v4*>(&sb1h[ob]);
        ba0 = b1p[0]; ba1 = b1p[1];
        bb0 = b1p[0]; bb1 = b1p[1];
    }

    // GRU: 5 channels per lane, ROLLED (dynamic index -> LDS only)
    for (int i = 0; i < 5; i++) {
        int c = q * 5 + i;
        float ir0, ir1, iz0, iz1, in0, in1, hr0, hr1, hz0, hz1, hn0, hn1;
        dot20_dualv((const v4*)&sWih[c * 20],        ga0, ga1, ga2, ga3, ga4,
                    gb0, gb1, gb2, gb3, gb4, ir0, ir1);
        dot20_dualv((const v4*)&sWih[(20 + c) * 20], ga0, ga1, ga2, ga3, ga4,
                    gb0, gb1, gb2, gb3, gb4, iz0, iz1);
        dot20_dualv((const v4*)&sWih[(40 + c) * 20], ga0, ga1, ga2, ga3, ga4,
                    gb0, gb1, gb2, gb3, gb4, in0, in1);
        dot20_dualv((const v4*)&sWhh[c * 20],        va0, va1, va2, va3, va4,
                    vb0, vb1, vb2, vb3, vb4, hr0, hr1);
        dot20_dualv((const v4*)&sWhh[(20 + c) * 20], va0, va1, va2, va3, va4,
                    vb0, vb1, vb2, vb3, vb4, hz0, hz1);
        dot20_dualv((const v4*)&sWhh[(40 + c) * 20], va0, va1, va2, va3, va4,
                    vb0, vb1, vb2, vb3, vb4, hn0, hn1);
        float bi_r = sbih[c], bi_z = sbih[20 + c], bi_n = sbih[40 + c];
        float bh_r = sbhh[c], bh_z = sbhh[20 + c], bh_n = sbhh[40 + c];
        float nh0, nh1;
        {
            float r = sigmoid_f(bi_r + ir0 + bh_r + hr0);
            float z = sigmoid_f(bi_z + iz0 + bh_z + hz0);
            float xn = bi_n + in0 + r * (bh_n + hn0);
            xn = fminf(fmaxf(xn, -20.f), 20.f);
            float tt = __expf(2.f * xn);
            float n = (tt - 1.f) / (tt + 1.f);
            float hc = h_in[(size_t)e0 * NF + c];
            nh0 = (1.f - z) * n + z * hc;
            h_out[(size_t)e0 * NF + c] = nh0;
        }
        {
            float r = sigmoid_f(bi_r + ir1 + bh_r + hr1);
            float z = sigmoid_f(bi_z + iz1 + bh_z + hz1);
            float xn = bi_n + in1 + r * (bh_n + hn1);
            xn = fminf(fmaxf(xn, -20.f), 20.f);
            float tt = __expf(2.f * xn);
            float n = (tt - 1.f) / (tt + 1.f);
            float hc = h_in[(size_t)e1 * NF + c];
            nh1 = (1.f - z) * n + z * hc;
            h_out[(size_t)e1 * NF + c] = nh1;
        }
        if (WRITEB) {
            // DPP quad broadcast of the 4 channels produced this iteration
            #define WB1(qq) { \
                float f0_ = dppf<(qq)*0x55>(nh0); \
                float f1_ = dppf<(qq)*0x55>(nh1); \
                const v4* wp_ = reinterpret_cast<const v4*>(&sW1h[((qq)*5 + i) * 32 + ob]); \
                v4 w0_ = wp_[0], w1_ = wp_[1]; \
                v4 t0_ = bc4(f0_), t1_ = bc4(f1_); \
                ba0 = EWFMA(t0_, w0_, ba0); ba1 = EWFMA(t0_, w1_, ba1); \
                bb0 = EWFMA(t1_, w0_, bb0); bb1 = EWFMA(t1_, w1_, bb1); }
            WB1(0) WB1(1) WB1(2) WB1(3)
            #undef WB1
        }
    }
    if (WRITEB) {
        uint4* Bo = reinterpret_cast<uint4*>(Bw);
        Bo[(size_t)e0 * 4 + q] = f8_to_h8(ba0, ba1);
        Bo[(size_t)e1 * 4 + q] = f8_to_h8(bb0, bb1);
    }
}

// Last step + fused readout. No h_out global writes: nh goes to LDS, then the
// dead message/GRU weight LDS region is overlaid with readout weights and
// 2 threads/edge compute the MLP (o-range split, DPP xor1 combine).
__global__ void __launch_bounds__(256) kernel_step_ro(
    const float* __restrict__ h_in,
    const __half* __restrict__ Br, const int* __restrict__ dst,
    const float* __restrict__ W1, const float* __restrict__ W2, const float* __restrict__ b2,
    const float* __restrict__ Wih, const float* __restrict__ Whh,
    const float* __restrict__ bih, const float* __restrict__ bhh,
    const float* __restrict__ roW1, const float* __restrict__ rob1,
    const float* __restrict__ roW2, const float* __restrict__ rob2,
    const float* __restrict__ roW3, const float* __restrict__ rob3,
    float* __restrict__ out)
{
    // phase1 layout:  sW1 0 | sW2 640 | sb2v 1280 | sCorr 1300 | sWih 1320
    //                 sWhh 2520 | sbih 3720 | sbhh 3780   (total 3840)
    // phase2 overlay: roW1 0 (1280) | rob1 1280 (64) | roW2 1344 (2048)
    //                 rob2 3392 (32) | roW3 3424 (32) | rob3 3456
    __shared__ __align__(16) float S[3840];
    __shared__ __align__(16) float sh[2560];   // 128 edges x 20 (final h)
    float* sW1  = S;
    float* sW2  = S + 640;
    float* sb2v = S + 1280;
    float* sCorr= S + 1300;
    float* sWih = S + 1320;
    float* sWhh = S + 2520;
    float* sbih = S + 3720;
    float* sbhh = S + 3780;

    for (int i = threadIdx.x; i < 640; i += 256) {
        sW1[i] = W1[i] * LOG2E_F;
        sW2[i] = W2[i];
    }
    for (int i = threadIdx.x; i < 1200; i += 256) { sWih[i] = Wih[i]; sWhh[i] = Whh[i]; }
    if (threadIdx.x < 20) sb2v[threadIdx.x] = b2[threadIdx.x];
    else if (threadIdx.x >= 64 && threadIdx.x < 124) sbih[threadIdx.x - 64] = bih[threadIdx.x - 64];
    else if (threadIdx.x >= 128 && threadIdx.x < 188) sbhh[threadIdx.x - 128] = bhh[threadIdx.x - 128];
    __syncthreads();
    if (threadIdx.x < 20) {
        float s = 0.f;
        #pragma unroll
        for (int o = 0; o < 32; o++) s += sW2[o * 20 + threadIdx.x];
        sCorr[threadIdx.x] = 16.f * (sb2v[threadIdx.x] - SELU_KA * s);
    }
    __syncthreads();

    int t = blockIdx.x * 256 + threadIdx.x;
    int p = t >> 2;
    int q = t & 3;
    int ob = q * 8;
    int e0 = p * 2, e1 = p * 2 + 1;
    int lp = threadIdx.x >> 2;
    int el0 = lp * 2, el1 = lp * 2 + 1;

    int2 dd = *reinterpret_cast<const int2*>(dst + e0);
    int d0 = dd.x, d1 = dd.y;

    const v4* hp0 = reinterpret_cast<const v4*>(h_in + (size_t)e0 * NF);
    const v4* hp1 = reinterpret_cast<const v4*>(h_in + (size_t)e1 * NF);
    v4 va0 = hp0[0], va1 = hp0[1], va2 = hp0[2], va3 = hp0[3], va4 = hp0[4];
    v4 vb0 = hp1[0], vb1 = hp1[1], vb2 = hp1[2], vb3 = hp1[3], vb4 = hp1[4];

    v4 aa0 = v4z(), aa1 = v4z(), ab0 = v4z(), ab1 = v4z();
    #define ASTEP2(f, h0, h1) { const v4* w_ = (const v4*)&sW1[(f)*32 + ob]; \
        v4 w0_ = w_[0], w1_ = w_[1]; \
        v4 t0_ = bc4(h0), t1_ = bc4(h1); \
        aa0 = EWFMA(t0_, w0_, aa0); aa1 = EWFMA(t0_, w1_, aa1); \
        ab0 = EWFMA(t1_, w0_, ab0); ab1 = EWFMA(t1_, w1_, ab1); }
    FOR20_2(ASTEP2)
    #undef ASTEP2

    const uint4* Bp0 = reinterpret_cast<const uint4*>(Br) + (size_t)d0 * 64 + q;
    const uint4* Bp1 = reinterpret_cast<const uint4*>(Br) + (size_t)d1 * 64 + q;
    v4 sa0 = v4z(), sa1 = v4z(), sb0 = v4z(), sb1 = v4z();
    {
        v4 kav = bc4(SELU_KA), scv = bc4(SELU_SC2), z4 = v4z();
        #define SELUACC(s_, a_, b_) { v4 x_ = (a_) + (b_); \
            v4 p_ = EWMAX(x_, z4); v4 m_ = EWMIN(x_, z4); \
            v4 e_ = {EX2F(m_.x), EX2F(m_.y), EX2F(m_.z), EX2F(m_.w)}; \
            s_ = EWFMA(kav, e_, s_); s_ = EWFMA(scv, p_, s_); }
        #pragma unroll 4
        for (int k = 0; k < 16; k++) {
            uint4 rA = Bp0[k * 4];
            uint4 rB = Bp1[k * 4];
            v4 loA, hiA, loB, hiB;
            h8_to_v4x2(rA, loA, hiA);
            h8_to_v4x2(rB, loB, hiB);
            SELUACC(sa0, aa0, loA);
            SELUACC(sa1, aa1, hiA);
            SELUACC(sb0, ab0, loB);
            SELUACC(sb1, ab1, hiB);
        }
        #undef SELUACC
    }

    v4 ga0 = v4z(), ga1 = v4z(), ga2 = v4z(), ga3 = v4z(), ga4 = v4z();
    v4 gb0 = v4z(), gb1 = v4z(), gb2 = v4z(), gb3 = v4z(), gb4 = v4z();
    #define AGGS2(j, c0_, c1_) { const v4* w_ = (const v4*)&sW2[(ob + (j)) * 20]; \
        v4 w0_ = w_[0], w1_ = w_[1], w2_ = w_[2], w3_ = w_[3], w4_ = w_[4]; \
        v4 u_ = bc4(c0_), vv_ = bc4(c1_); \
        ga0 = EWFMA(u_, w0_, ga0); ga1 = EWFMA(u_, w1_, ga1); ga2 = EWFMA(u_, w2_, ga2); \
        ga3 = EWFMA(u_, w3_, ga3); ga4 = EWFMA(u_, w4_, ga4); \
        gb0 = EWFMA(vv_, w0_, gb0); gb1 = EWFMA(vv_, w1_, gb1); gb2 = EWFMA(vv_, w2_, gb2); \
        gb3 = EWFMA(vv_, w3_, gb3); gb4 = EWFMA(vv_, w4_, gb4); }
    FOR8S2(AGGS2)
    #undef AGGS2

    #define BFLY(CTRL) { \
        ga0 = ga0 + dpp4<CTRL>(ga0); ga1 = ga1 + dpp4<CTRL>(ga1); \
        ga2 = ga2 + dpp4<CTRL>(ga2); ga3 = ga3 + dpp4<CTRL>(ga3); \
        ga4 = ga4 + dpp4<CTRL>(ga4); \
        gb0 = gb0 + dpp4<CTRL>(gb0); gb1 = gb1 + dpp4<CTRL>(gb1); \
        gb2 = gb2 + dpp4<CTRL>(gb2); gb3 = gb3 + dpp4<CTRL>(gb3); \
        gb4 = gb4 + dpp4<CTRL>(gb4); }
    BFLY(DPP_XOR1)
    BFLY(DPP_XOR2)
    #undef BFLY

    {
        const v4* cp = reinterpret_cast<const v4*>(sCorr);
        v4 c0 = cp[0], c1 = cp[1], c2 = cp[2], c3 = cp[3], c4 = cp[4];
        ga0 = ga0 + c0; ga1 = ga1 + c1; ga2 = ga2 + c2; ga3 = ga3 + c3; ga4 = ga4 + c4;
        gb0 = gb0 + c0; gb1 = gb1 + c1; gb2 = gb2 + c2; gb3 = gb3 + c3; gb4 = gb4 + c4;
    }

    for (int i = 0; i < 5; i++) {
        int c = q * 5 + i;
        float ir0, ir1, iz0, iz1, in0, in1, hr0, hr1, hz0, hz1, hn0, hn1;
        dot20_dualv((const v4*)&sWih[c * 20],        ga0, ga1, ga2, ga3, ga4,
                    gb0, gb1, gb2, gb3, gb4, ir0, ir1);
        dot20_dualv((const v4*)&sWih[(20 + c) * 20], ga0, ga1, ga2, ga3, ga4,
                    gb0, gb1, gb2, gb3, gb4, iz0, iz1);
        dot20_dualv((const v4*)&sWih[(40 + c) * 20], ga0, ga1, ga2, ga3, ga4,
                    gb0, gb1, gb2, gb3, gb4, in0, in1);
        dot20_dualv((const v4*)&sWhh[c * 20],        va0, va1, va2, va3, va4,
                    vb0, vb1, vb2, vb3, vb4, hr0, hr1);
        dot20_dualv((const v4*)&sWhh[(20 + c) * 20], va0, va1, va2, va3, va4,
                    vb0, vb1, vb2, vb3, vb4, hz0, hz1);
        dot20_dualv((const v4*)&sWhh[(40 + c) * 20], va0, va1, va2, va3, va4,
                    vb0, vb1, vb2, vb3, vb4, hn0, hn1);
        float bi_r = sbih[c], bi_z = sbih[20 + c], bi_n = sbih[40 + c];
        float bh_r = sbhh[c], bh_z = sbhh[20 + c], bh_n = sbhh[40 + c];
        {
            float r = sigmoid_f(bi_r + ir0 + bh_r + hr0);
            float z = sigmoid_f(bi_z + iz0 + bh_z + hz0);
            float xn = bi_n + in0 + r * (bh_n + hn0);
            xn = fminf(fmaxf(xn, -20.f), 20.f);
            float tt = __expf(2.f * xn);
            float n = (tt - 1.f) / (tt + 1.f);
            float hc = h_in[(size_t)e0 * NF + c];
            sh[el0 * 20 + c] = (1.f - z) * n + z * hc;
        }
        {
            float r = sigmoid_f(bi_r + ir1 + bh_r + hr1);
            float z = sigmoid_f(bi_z + iz1 + bh_z + hz1);
            float xn = bi_n + in1 + r * (bh_n + hn1);
            xn = fminf(fmaxf(xn, -20.f), 20.f);
            float tt = __expf(2.f * xn);
            float n = (tt - 1.f) / (tt + 1.f);
            float hc = h_in[(size_t)e1 * NF + c];
            sh[el1 * 20 + c] = (1.f - z) * n + z * hc;
        }
    }

    __syncthreads();   // all GRU weight reads + sh writes complete
    // overlay readout weights onto S
    for (int i = threadIdx.x; i < 1280; i += 256) S[i] = roW1[i];
    for (int i = threadIdx.x; i < 2048; i += 256) S[1344 + i] = roW2[i];
    {
        int tx = threadIdx.x;
        if (tx < 64) S[1280 + tx] = rob1[tx];
        else if (tx < 96) S[3392 + (tx - 64)] = rob2[tx - 64];
        else if (tx < 128) S[3424 + (tx - 96)] = roW3[tx - 96];
        else if (tx == 128) S[3456] = rob3[0];
    }
    __syncthreads();

    // readout: 2 threads per edge, each does 32 of the 64 hidden units
    {
        int el = threadIdx.x >> 1;
        int half = threadIdx.x & 1;
        int ob32 = half * 32;
        const v4* hp = reinterpret_cast<const v4*>(&sh[el * 20]);
        v4 v0 = hp[0], v1 = hp[1], v2 = hp[2], v3 = hp[3], v4v = hp[4];

        const v4* b1p = reinterpret_cast<const v4*>(&S[1280 + ob32]);
        v4 x0 = b1p[0], x1 = b1p[1], x2 = b1p[2], x3 = b1p[3],
           x4 = b1p[4], x5 = b1p[5], x6 = b1p[6], x7 = b1p[7];
        #define ROS(f, hf) { v4 t_ = bc4(hf); const v4* w_ = (const v4*)&S[(f)*64 + ob32]; \
            x0 = EWFMA(t_, w_[0], x0); x1 = EWFMA(t_, w_[1], x1); \
            x2 = EWFMA(t_, w_[2], x2); x3 = EWFMA(t_, w_[3], x3); \
            x4 = EWFMA(t_, w_[4], x4); x5 = EWFMA(t_, w_[5], x5); \
            x6 = EWFMA(t_, w_[6], x6); x7 = EWFMA(t_, w_[7], x7); }
        FOR20(ROS)
        #undef ROS
        x0 = selu4(x0); x1 = selu4(x1); x2 = selu4(x2); x3 = selu4(x3);
        x4 = selu4(x4); x5 = selu4(x5); x6 = selu4(x6); x7 = selu4(x7);

        const v4* b2p = reinterpret_cast<const v4*>(&S[3392]);
        v4 y0, y1, y2, y3, y4, y5, y6, y7;
        if (half == 0) {
            y0 = b2p[0]; y1 = b2p[1]; y2 = b2p[2]; y3 = b2p[3];
            y4 = b2p[4]; y5 = b2p[5]; y6 = b2p[6]; y7 = b2p[7];
        } else {
            y0 = v4z(); y1 = v4z(); y2 = v4z(); y3 = v4z();
            y4 = v4z(); y5 = v4z(); y6 = v4z(); y7 = v4z();
        }
        #define Y8(s_, o_) { const v4* w_ = reinterpret_cast<const v4*>(&S[1344 + (o_)*32]); \
            v4 t_ = bc4(s_); \
            y0 = EWFMA(t_, w_[0], y0); y1 = EWFMA(t_, w_[1], y1); \
            y2 = EWFMA(t_, w_[2], y2); y3 = EWFMA(t_, w_[3], y3); \
            y4 = EWFMA(t_, w_[4], y4); y5 = EWFMA(t_, w_[5], y5); \
            y6 = EWFMA(t_, w_[6], y6); y7 = EWFMA(t_, w_[7], y7); }
        #define S2V(jj, xv) Y8(xv.x, ob32+(jj)*4+0) Y8(xv.y, ob32+(jj)*4+1) \
                            Y8(xv.z, ob32+(jj)*4+2) Y8(xv.w, ob32+(jj)*4+3)
        S2V(0, x0) S2V(1, x1) S2V(2, x2) S2V(3, x3)
        S2V(4, x4) S2V(5, x5) S2V(6, x6) S2V(7, x7)
        #undef S2V
        #undef Y8

        // combine the two halves (partner = tid^1, same edge) via DPP xor1
        y0 = y0 + dpp4<DPP_XOR1>(y0); y1 = y1 + dpp4<DPP_XOR1>(y1);
        y2 = y2 + dpp4<DPP_XOR1>(y2); y3 = y3 + dpp4<DPP_XOR1>(y3);
        y4 = y4 + dpp4<DPP_XOR1>(y4); y5 = y5 + dpp4<DPP_XOR1>(y5);
        y6 = y6 + dpp4<DPP_XOR1>(y6); y7 = y7 + dpp4<DPP_XOR1>(y7);

        const v4* w3p = reinterpret_cast<const v4*>(&S[3424]);
        v4 accv = selu4(y0) * w3p[0];
        accv = EWFMA(selu4(y1), w3p[1], accv);
        accv = EWFMA(selu4(y2), w3p[2], accv);
        accv = EWFMA(selu4(y3), w3p[3], accv);
        accv = EWFMA(selu4(y4), w3p[4], accv);
        accv = EWFMA(selu4(y5), w3p[5], accv);
        accv = EWFMA(selu4(y6), w3p[6], accv);
        accv = EWFMA(selu4(y7), w3p[7], accv);
        float acc = S[3456] + hsum4(accv);
        float sp = fmaxf(acc, 0.f) + log1pf(__expf(-fabsf(acc)));
        float wv = sp + 0.1f;
        wv = fminf(fmaxf(wv, 0.1f), 10.f);
        if (half == 0) out[blockIdx.x * 128 + el] = wv;
    }
}

extern "C" void kernel_launch(void* const* d_in, const int* in_sizes, int n_in,
                              void* d_out, int out_size, void* d_ws, size_t ws_size,
                              hipStream_t stream) {
    const float* edge_attr = (const float*)d_in[0];
    const float* msg_W1   = (const float*)d_in[1];
    const float* msg_b1   = (const float*)d_in[2];
    const float* msg_W2   = (const float*)d_in[3];
    const float* msg_b2   = (const float*)d_in[4];
    const float* gru_Wih  = (const float*)d_in[5];
    const float* gru_Whh  = (const float*)d_in[6];
    const float* gru_bih  = (const float*)d_in[7];
    const float* gru_bhh  = (const float*)d_in[8];
    const float* ro_W1    = (const float*)d_in[9];
    const float* ro_b1    = (const float*)d_in[10];
    const float* ro_W2    = (const float*)d_in[11];
    const float* ro_b2    = (const float*)d_in[12];
    const float* ro_W3    = (const float*)d_in[13];
    const float* ro_b3    = (const float*)d_in[14];
    const int* edge_index = (const int*)d_in[15];
    const int* dst = edge_index + E_EDGES;   // row 1 of (2,E)

    float*  h_ws = (float*)d_ws;                                  // E*20 f32
    __half* BtA  = (__half*)(h_ws + (size_t)E_EDGES * NF);        // E*32 f16
    __half* BtB  = BtA + (size_t)E_EDGES * 32;                    // E*32 f16 (ping-pong)

    size_t need = (size_t)E_EDGES * NF * sizeof(float)
                + 2 * (size_t)E_EDGES * 32 * sizeof(__half);
    bool fused = ws_size >= need;

    dim3 block(256);
    dim3 gridB(E_EDGES / 256);
    dim3 gridS(E_EDGES * 2 / 256);     // 4 lanes per 2-edge pair

    kernel_B0<<<gridB, block, 0, stream>>>(edge_attr, msg_W1, msg_b1, BtA);

    const float* hin = edge_attr;
    __half* Bin = BtA;
    __half* Bout = BtB;
    for (int s = 0; s < 3; s++) {
        if (!fused && s > 0)
            kernel_B0<<<gridB, block, 0, stream>>>(hin, msg_W1, msg_b1, BtA);
        if (fused) {
            kernel_stepT<true><<<gridS, block, 0, stream>>>(hin, h_ws, Bin, dst,
                msg_W1, msg_b1, msg_W2, msg_b2, gru_Wih, gru_Whh, gru_bih, gru_bhh,
                Bout);
            __half* tmp = Bin; Bin = Bout; Bout = tmp;
        } else {
            kernel_stepT<false><<<gridS, block, 0, stream>>>(hin, h_ws, Bin, dst,
                msg_W1, msg_b1, msg_W2, msg_b2, gru_Wih, gru_Whh, gru_bih, gru_bhh,
                nullptr);
        }
        hin = h_ws;
    }
    if (!fused)
        kernel_B0<<<gridB, block, 0, stream>>>(hin, msg_W1, msg_b1, BtA);
    // last step + readout fused; no h_out global round-trip
    kernel_step_ro<<<gridS, block, 0, stream>>>(hin, Bin, dst,
        msg_W1, msg_W2, msg_b2, gru_Wih, gru_Whh, gru_bih, gru_bhh,
        ro_W1, ro_b1, ro_W2, ro_b2, ro_W3, ro_b3, (float*)d_out);
}

// Round 4
// 522.039 us; speedup vs baseline: 1.6245x; 1.6245x over previous
//
#include <hip/hip_runtime.h>
#include <hip/hip_fp16.h>

#define E_EDGES 320000
#define NF 20

typedef float v4 __attribute__((ext_vector_type(4)));
typedef float v2f __attribute__((ext_vector_type(2)));

#if defined(__has_builtin)
# if __has_builtin(__builtin_elementwise_fma)
#  define EWFMA(a,b,c) __builtin_elementwise_fma((a),(b),(c))
# endif
#endif
#ifndef EWFMA
# define EWFMA(a,b,c) ((a)*(b)+(c))
#endif
#if defined(__has_builtin)
# if __has_builtin(__builtin_elementwise_max)
#  define EWMAX(a,b) __builtin_elementwise_max((a),(b))
#  define EWMIN(a,b) __builtin_elementwise_min((a),(b))
# endif
#endif

#if defined(__has_builtin)
# if __has_builtin(__builtin_amdgcn_exp2f)
#  define EX2F(x) __builtin_amdgcn_exp2f(x)
# endif
#endif
#ifndef EX2F
# define EX2F(x) exp2f(x)
#endif

#define LOG2E_F 1.4426950408889634f
#define SELU_SCALE 1.0507009873554805f
#define SELU_ALPHA 1.6732632423543772f
#define SELU_KA (SELU_SCALE * SELU_ALPHA)             /* scale*alpha */
#define SELU_SC2 (SELU_SCALE / LOG2E_F)               /* scale / log2e */

__device__ __forceinline__ v4 bc4(float s) { return (v4){s, s, s, s}; }
__device__ __forceinline__ v4 v4z() { return (v4){0.f, 0.f, 0.f, 0.f}; }

// DPP quad_perm helpers (VALU cross-lane, no LDS pipe)
#define DPP_XOR1 0xB1   /* quad_perm [1,0,3,2] */
#define DPP_XOR2 0x4E   /* quad_perm [2,3,0,1] */
template<int CTRL>
__device__ __forceinline__ float dppf(float x) {
    return __builtin_bit_cast(float,
        __builtin_amdgcn_update_dpp(0, __builtin_bit_cast(int, x), CTRL, 0xF, 0xF, true));
}
template<int CTRL>
__device__ __forceinline__ v4 dpp4(v4 x) {
    v4 r;
    r.x = dppf<CTRL>(x.x); r.y = dppf<CTRL>(x.y);
    r.z = dppf<CTRL>(x.z); r.w = dppf<CTRL>(x.w);
    return r;
}

__device__ __forceinline__ float selu_f(float x) {
    const float scale = SELU_SCALE;
    const float alpha = SELU_ALPHA;
    float p = fmaxf(x, 0.f);
    float m = fminf(x, 0.f);
    float e = __expf(m);
    return fmaf(scale, p, scale * alpha * (e - 1.f));
}
__device__ __forceinline__ float sigmoid_f(float x) {
    return 1.f / (1.f + __expf(-x));
}
// packed selu (used by readout only)
__device__ __forceinline__ v4 selu4(v4 x) {
    const float scale = SELU_SCALE;
    const float ka = SELU_KA;
#ifdef EWMAX
    v4 p = EWMAX(x, v4z());
    v4 m = EWMIN(x, v4z());
#else
    v4 p = {fmaxf(x.x,0.f), fmaxf(x.y,0.f), fmaxf(x.z,0.f), fmaxf(x.w,0.f)};
    v4 m = {fminf(x.x,0.f), fminf(x.y,0.f), fminf(x.z,0.f), fminf(x.w,0.f)};
#endif
    v4 e = {__expf(m.x), __expf(m.y), __expf(m.z), __expf(m.w)};
    return EWFMA(bc4(scale), p, EWFMA(bc4(ka), e, bc4(-ka)));
}

__device__ __forceinline__ float hsum4(v4 x) {
    v2f lo = __builtin_shufflevector(x, x, 0, 1);
    v2f hi = __builtin_shufflevector(x, x, 2, 3);
    v2f h = lo + hi;
    return h.x + h.y;
}

__device__ __forceinline__ float dot20v(v4 a0, v4 a1, v4 a2, v4 a3, v4 a4,
                                        const v4* __restrict__ w) {
    v4 w0 = w[0], w1 = w[1], w2 = w[2], w3 = w[3], w4 = w[4];
    v4 x = a0 * w0;
    x = EWFMA(a1, w1, x); x = EWFMA(a2, w2, x);
    x = EWFMA(a3, w3, x); x = EWFMA(a4, w4, x);
    return hsum4(x);
}
// one LDS row read serves BOTH edges, vertical pk-fma then horizontal reduce
__device__ __forceinline__ void dot20_dualv(const v4* __restrict__ w,
    v4 a0, v4 a1, v4 a2, v4 a3, v4 a4,
    v4 b0, v4 b1, v4 b2, v4 b3, v4 b4,
    float& r0, float& r1)
{
    v4 w0 = w[0], w1 = w[1], w2 = w[2], w3 = w[3], w4 = w[4];
    v4 xa = a0 * w0;
    xa = EWFMA(a1, w1, xa); xa = EWFMA(a2, w2, xa);
    xa = EWFMA(a3, w3, xa); xa = EWFMA(a4, w4, xa);
    v4 xb = b0 * w0;
    xb = EWFMA(b1, w1, xb); xb = EWFMA(b2, w2, xb);
    xb = EWFMA(b3, w3, xb); xb = EWFMA(b4, w4, xb);
    r0 = hsum4(xa);
    r1 = hsum4(xb);
}
__device__ __forceinline__ void h8_to_v4x2(uint4 r, v4& lo, v4& hi) {
    float2 fa = __half22float2(__builtin_bit_cast(__half2, r.x));
    float2 fb = __half22float2(__builtin_bit_cast(__half2, r.y));
    float2 fc = __half22float2(__builtin_bit_cast(__half2, r.z));
    float2 fd = __half22float2(__builtin_bit_cast(__half2, r.w));
    lo = (v4){fa.x, fa.y, fb.x, fb.y};
    hi = (v4){fc.x, fc.y, fd.x, fd.y};
}
__device__ __forceinline__ uint4 f8_to_h8(v4 lo, v4 hi) {
    uint4 r;
    r.x = __builtin_bit_cast(unsigned, __floats2half2_rn(lo.x, lo.y));
    r.y = __builtin_bit_cast(unsigned, __floats2half2_rn(lo.z, lo.w));
    r.z = __builtin_bit_cast(unsigned, __floats2half2_rn(hi.x, hi.y));
    r.w = __builtin_bit_cast(unsigned, __floats2half2_rn(hi.z, hi.w));
    return r;
}

#define FOR20(X) \
  X(0, v0.x) X(1, v0.y) X(2, v0.z) X(3, v0.w) \
  X(4, v1.x) X(5, v1.y) X(6, v1.z) X(7, v1.w) \
  X(8, v2.x) X(9, v2.y) X(10, v2.z) X(11, v2.w) \
  X(12, v3.x) X(13, v3.y) X(14, v3.z) X(15, v3.w) \
  X(16, v4v.x) X(17, v4v.y) X(18, v4v.z) X(19, v4v.w)

#define FOR20_2(X) \
  X(0, va0.x, vb0.x) X(1, va0.y, vb0.y) X(2, va0.z, vb0.z) X(3, va0.w, vb0.w) \
  X(4, va1.x, vb1.x) X(5, va1.y, vb1.y) X(6, va1.z, vb1.z) X(7, va1.w, vb1.w) \
  X(8, va2.x, vb2.x) X(9, va2.y, vb2.y) X(10, va2.z, vb2.z) X(11, va2.w, vb2.w) \
  X(12, va3.x, vb3.x) X(13, va3.y, vb3.y) X(14, va3.z, vb3.z) X(15, va3.w, vb3.w) \
  X(16, va4.x, vb4.x) X(17, va4.y, vb4.y) X(18, va4.z, vb4.z) X(19, va4.w, vb4.w)

#define FOR8S2(X) \
  X(0, sa0.x, sb0.x) X(1, sa0.y, sb0.y) X(2, sa0.z, sb0.z) X(3, sa0.w, sb0.w) \
  X(4, sa1.x, sb1.x) X(5, sa1.y, sb1.y) X(6, sa1.z, sb1.z) X(7, sa1.w, sb1.w)

// B[e][o] = (sum_f h[e][f] * W1[20+f][o] + b1[o]) * log2e, fp16 output.
// log2e pre-scale lets kernel_step's selu use raw v_exp_f32 (2^x), no per-elem mul.
__global__ void __launch_bounds__(256) kernel_B0(
    const float* __restrict__ h, const float* __restrict__ W1,
    const float* __restrict__ b1, __half* __restrict__ B)
{
    __shared__ __align__(16) float sw[640];
    __shared__ __align__(16) float sbias[32];
    for (int i = threadIdx.x; i < 640; i += 256) sw[i] = W1[640 + i] * LOG2E_F;
    if (threadIdx.x < 32) sbias[threadIdx.x] = b1[threadIdx.x] * LOG2E_F;
    __syncthreads();
    int e = blockIdx.x * 256 + threadIdx.x;
    const v4* hp = reinterpret_cast<const v4*>(h + (size_t)e * NF);
    v4 v0 = hp[0], v1 = hp[1], v2 = hp[2], v3 = hp[3], v4v = hp[4];
    const v4* bi = reinterpret_cast<const v4*>(sbias);
    v4 c0 = bi[0], c1 = bi[1], c2 = bi[2], c3 = bi[3],
       c4 = bi[4], c5 = bi[5], c6 = bi[6], c7 = bi[7];
    #define BSTEP(f, hf) { v4 t_ = bc4(hf); const v4* w_ = (const v4*)&sw[(f)*32]; \
        c0 = EWFMA(t_, w_[0], c0); c1 = EWFMA(t_, w_[1], c1); \
        c2 = EWFMA(t_, w_[2], c2); c3 = EWFMA(t_, w_[3], c3); \
        c4 = EWFMA(t_, w_[4], c4); c5 = EWFMA(t_, w_[5], c5); \
        c6 = EWFMA(t_, w_[6], c6); c7 = EWFMA(t_, w_[7], c7); }
    FOR20(BSTEP)
    #undef BSTEP
    uint4* Bp = reinterpret_cast<uint4*>(B + (size_t)e * 32);
    Bp[0] = f8_to_h8(c0, c1); Bp[1] = f8_to_h8(c2, c3);
    Bp[2] = f8_to_h8(c4, c5); Bp[3] = f8_to_h8(c6, c7);
}

// One step. 4 lanes/quad, 2 edges/thread, fp16 B gather (log2e-scaled),
// rolled GRU, DPP quad exchanges. WRITEB emits next step's B tile.
template<bool WRITEB>
__global__ void __launch_bounds__(256) kernel_stepT(
    const float* __restrict__ h_in, float* __restrict__ h_out,
    const __half* __restrict__ Br, const int* __restrict__ dst,
    const float* __restrict__ W1, const float* __restrict__ b1,
    const float* __restrict__ W2, const float* __restrict__ b2,
    const float* __restrict__ Wih, const float* __restrict__ Whh,
    const float* __restrict__ bih, const float* __restrict__ bhh,
    __half* __restrict__ Bw)
{
    __shared__ __align__(16) float sW1[640];   // rows 0-19 of msg_W1 (20,32), *log2e
    __shared__ __align__(16) float sW1h[640];  // rows 20-39 of msg_W1, *log2e (B-fuse)
    __shared__ __align__(16) float sb1h[32];   // b1 * log2e (B-fuse)
    __shared__ __align__(16) float sW2[640];   // (32,20)
    __shared__ __align__(16) float sb2v[20];
    __shared__ __align__(16) float sCorr[20];  // 16*(b2 - KA*colsum(W2))
    __shared__ __align__(16) float sWih[1200]; // (60,20)
    __shared__ __align__(16) float sWhh[1200];
    __shared__ float sbih[60];
    __shared__ float sbhh[60];
    for (int i = threadIdx.x; i < 640; i += 256) {
        sW1[i] = W1[i] * LOG2E_F;
        sW2[i] = W2[i];
        if (WRITEB) sW1h[i] = W1[640 + i] * LOG2E_F;
    }
    for (int i = threadIdx.x; i < 1200; i += 256) { sWih[i] = Wih[i]; sWhh[i] = Whh[i]; }
    if (threadIdx.x < 20) sb2v[threadIdx.x] = b2[threadIdx.x];
    else if (threadIdx.x >= 64 && threadIdx.x < 124) sbih[threadIdx.x - 64] = bih[threadIdx.x - 64];
    else if (threadIdx.x >= 128 && threadIdx.x < 188) sbhh[threadIdx.x - 128] = bhh[threadIdx.x - 128];
    else if (WRITEB && threadIdx.x >= 192 && threadIdx.x < 224)
        sb1h[threadIdx.x - 192] = b1[threadIdx.x - 192] * LOG2E_F;
    __syncthreads();
    if (threadIdx.x < 20) {
        float s = 0.f;
        #pragma unroll
        for (int o = 0; o < 32; o++) s += sW2[o * 20 + threadIdx.x];
        sCorr[threadIdx.x] = 16.f * (sb2v[threadIdx.x] - SELU_KA * s);
    }
    __syncthreads();

    int t = blockIdx.x * 256 + threadIdx.x;
    int p = t >> 2;
    int q = t & 3;
    int ob = q * 8;
    int e0 = p * 2, e1 = p * 2 + 1;

    int2 dd = *reinterpret_cast<const int2*>(dst + e0);
    int d0 = dd.x, d1 = dd.y;

    const v4* hp0 = reinterpret_cast<const v4*>(h_in + (size_t)e0 * NF);
    const v4* hp1 = reinterpret_cast<const v4*>(h_in + (size_t)e1 * NF);
    v4 va0 = hp0[0], va1 = hp0[1], va2 = hp0[2], va3 = hp0[3], va4 = hp0[4];
    v4 vb0 = hp1[0], vb1 = hp1[1], vb2 = hp1[2], vb3 = hp1[3], vb4 = hp1[4];

    // A' slices for both edges (already log2e-scaled via sW1 staging)
    v4 aa0 = v4z(), aa1 = v4z(), ab0 = v4z(), ab1 = v4z();
    #define ASTEP2(f, h0, h1) { const v4* w_ = (const v4*)&sW1[(f)*32 + ob]; \
        v4 w0_ = w_[0], w1_ = w_[1]; \
        v4 t0_ = bc4(h0), t1_ = bc4(h1); \
        aa0 = EWFMA(t0_, w0_, aa0); aa1 = EWFMA(t0_, w1_, aa1); \
        ab0 = EWFMA(t1_, w0_, ab0); ab1 = EWFMA(t1_, w1_, ab1); }
    FOR20_2(ASTEP2)
    #undef ASTEP2

    // gather 16 fp16 rows per edge; folded selu accumulate
    const uint4* Bp0 = reinterpret_cast<const uint4*>(Br) + (size_t)d0 * 64 + q;
    const uint4* Bp1 = reinterpret_cast<const uint4*>(Br) + (size_t)d1 * 64 + q;
    v4 sa0 = v4z(), sa1 = v4z(), sb0 = v4z(), sb1 = v4z();
    {
        v4 kav = bc4(SELU_KA), scv = bc4(SELU_SC2), z4 = v4z();
        #define SELUACC(s_, a_, b_) { v4 x_ = (a_) + (b_); \
            v4 p_ = EWMAX(x_, z4); v4 m_ = EWMIN(x_, z4); \
            v4 e_ = {EX2F(m_.x), EX2F(m_.y), EX2F(m_.z), EX2F(m_.w)}; \
            s_ = EWFMA(kav, e_, s_); s_ = EWFMA(scv, p_, s_); }
        #pragma unroll 4
        for (int k = 0; k < 16; k++) {
            uint4 rA = Bp0[k * 4];
            uint4 rB = Bp1[k * 4];
            v4 loA, hiA, loB, hiB;
            h8_to_v4x2(rA, loA, hiA);
            h8_to_v4x2(rB, loB, hiB);
            SELUACC(sa0, aa0, loA);
            SELUACC(sa1, aa1, hiA);
            SELUACC(sb0, ab0, loB);
            SELUACC(sb1, ab1, hiB);
        }
        #undef SELUACC
    }

    // partial agg (shared W2 rows, pk-fma)
    v4 ga0 = v4z(), ga1 = v4z(), ga2 = v4z(), ga3 = v4z(), ga4 = v4z();
    v4 gb0 = v4z(), gb1 = v4z(), gb2 = v4z(), gb3 = v4z(), gb4 = v4z();
    #define AGGS2(j, c0_, c1_) { const v4* w_ = (const v4*)&sW2[(ob + (j)) * 20]; \
        v4 w0_ = w_[0], w1_ = w_[1], w2_ = w_[2], w3_ = w_[3], w4_ = w_[4]; \
        v4 u_ = bc4(c0_), vv_ = bc4(c1_); \
        ga0 = EWFMA(u_, w0_, ga0); ga1 = EWFMA(u_, w1_, ga1); ga2 = EWFMA(u_, w2_, ga2); \
        ga3 = EWFMA(u_, w3_, ga3); ga4 = EWFMA(u_, w4_, ga4); \
        gb0 = EWFMA(vv_, w0_, gb0); gb1 = EWFMA(vv_, w1_, gb1); gb2 = EWFMA(vv_, w2_, gb2); \
        gb3 = EWFMA(vv_, w3_, gb3); gb4 = EWFMA(vv_, w4_, gb4); }
    FOR8S2(AGGS2)
    #undef AGGS2

    // quad butterfly via DPP (VALU only)
    #define BFLY(CTRL) { \
        ga0 = ga0 + dpp4<CTRL>(ga0); ga1 = ga1 + dpp4<CTRL>(ga1); \
        ga2 = ga2 + dpp4<CTRL>(ga2); ga3 = ga3 + dpp4<CTRL>(ga3); \
        ga4 = ga4 + dpp4<CTRL>(ga4); \
        gb0 = gb0 + dpp4<CTRL>(gb0); gb1 = gb1 + dpp4<CTRL>(gb1); \
        gb2 = gb2 + dpp4<CTRL>(gb2); gb3 = gb3 + dpp4<CTRL>(gb3); \
        gb4 = gb4 + dpp4<CTRL>(gb4); }
    BFLY(DPP_XOR1)
    BFLY(DPP_XOR2)
    #undef BFLY

    {
        const v4* cp = reinterpret_cast<const v4*>(sCorr);
        v4 c0 = cp[0], c1 = cp[1], c2 = cp[2], c3 = cp[3], c4 = cp[4];
        ga0 = ga0 + c0; ga1 = ga1 + c1; ga2 = ga2 + c2; ga3 = ga3 + c3; ga4 = ga4 + c4;
        gb0 = gb0 + c0; gb1 = gb1 + c1; gb2 = gb2 + c2; gb3 = gb3 + c3; gb4 = gb4 + c4;
    }

    // next-step B accumulators (8 output chans per lane per edge)
    v4 ba0, ba1, bb0, bb1;
    if (WRITEB) {
        const v4* b1p = reinterpret_cast<const v4*>(&sb1h[ob]);
        ba0 = b1p[0]; ba1 = b1p[1];
        bb0 = b1p[0]; bb1 = b1p[1];
    }

    // GRU: 5 channels per lane, ROLLED (dynamic index -> LDS only)
    for (int i = 0; i < 5; i++) {
        int c = q * 5 + i;
        float ir0, ir1, iz0, iz1, in0, in1, hr0, hr1, hz0, hz1, hn0, hn1;
        dot20_dualv((const v4*)&sWih[c * 20],        ga0, ga1, ga2, ga3, ga4,
                    gb0, gb1, gb2, gb3, gb4, ir0, ir1);
        dot20_dualv((const v4*)&sWih[(20 + c) * 20], ga0, ga1, ga2, ga3, ga4,
                    gb0, gb1, gb2, gb3, gb4, iz0, iz1);
        dot20_dualv((const v4*)&sWih[(40 + c) * 20], ga0, ga1, ga2, ga3, ga4,
                    gb0, gb1, gb2, gb3, gb4, in0, in1);
        dot20_dualv((const v4*)&sWhh[c * 20],        va0, va1, va2, va3, va4,
                    vb0, vb1, vb2, vb3, vb4, hr0, hr1);
        dot20_dualv((const v4*)&sWhh[(20 + c) * 20], va0, va1, va2, va3, va4,
                    vb0, vb1, vb2, vb3, vb4, hz0, hz1);
        dot20_dualv((const v4*)&sWhh[(40 + c) * 20], va0, va1, va2, va3, va4,
                    vb0, vb1, vb2, vb3, vb4, hn0, hn1);
        float bi_r = sbih[c], bi_z = sbih[20 + c], bi_n = sbih[40 + c];
        float bh_r = sbhh[c], bh_z = sbhh[20 + c], bh_n = sbhh[40 + c];
        float nh0, nh1;
        {
            float r = sigmoid_f(bi_r + ir0 + bh_r + hr0);
            float z = sigmoid_f(bi_z + iz0 + bh_z + hz0);
            float xn = bi_n + in0 + r * (bh_n + hn0);
            xn = fminf(fmaxf(xn, -20.f), 20.f);
            float tt = __expf(2.f * xn);
            float n = (tt - 1.f) / (tt + 1.f);
            float hc = h_in[(size_t)e0 * NF + c];
            nh0 = (1.f - z) * n + z * hc;
            h_out[(size_t)e0 * NF + c] = nh0;
        }
        {
            float r = sigmoid_f(bi_r + ir1 + bh_r + hr1);
            float z = sigmoid_f(bi_z + iz1 + bh_z + hz1);
            float xn = bi_n + in1 + r * (bh_n + hn1);
            xn = fminf(fmaxf(xn, -20.f), 20.f);
            float tt = __expf(2.f * xn);
            float n = (tt - 1.f) / (tt + 1.f);
            float hc = h_in[(size_t)e1 * NF + c];
            nh1 = (1.f - z) * n + z * hc;
            h_out[(size_t)e1 * NF + c] = nh1;
        }
        if (WRITEB) {
            // DPP quad broadcast of the 4 channels produced this iteration
            #define WB1(qq) { \
                float f0_ = dppf<(qq)*0x55>(nh0); \
                float f1_ = dppf<(qq)*0x55>(nh1); \
                const v4* wp_ = reinterpret_cast<const v4*>(&sW1h[((qq)*5 + i) * 32 + ob]); \
                v4 w0_ = wp_[0], w1_ = wp_[1]; \
                v4 t0_ = bc4(f0_), t1_ = bc4(f1_); \
                ba0 = EWFMA(t0_, w0_, ba0); ba1 = EWFMA(t0_, w1_, ba1); \
                bb0 = EWFMA(t1_, w0_, bb0); bb1 = EWFMA(t1_, w1_, bb1); }
            WB1(0) WB1(1) WB1(2) WB1(3)
            #undef WB1
        }
    }
    if (WRITEB) {
        uint4* Bo = reinterpret_cast<uint4*>(Bw);
        Bo[(size_t)e0 * 4 + q] = f8_to_h8(ba0, ba1);
        Bo[(size_t)e1 * 4 + q] = f8_to_h8(bb0, bb1);
    }
}

__global__ void __launch_bounds__(256) kernel_readout(
    const float* __restrict__ h,
    const float* __restrict__ W1, const float* __restrict__ b1,
    const float* __restrict__ W2, const float* __restrict__ b2,
    const float* __restrict__ W3, const float* __restrict__ b3,
    float* __restrict__ out)
{
    __shared__ __align__(16) float sW1t[1280]; // transposed: (64,20)
    __shared__ float sb1[64];
    __shared__ __align__(16) float sW2[2048];  // (64,32)
    __shared__ __align__(16) float sb2v[32];
    __shared__ __align__(16) float sW3[32];
    __shared__ float sb3;
    for (int i = threadIdx.x; i < 1280; i += 256) {
        int f = i >> 6, o = i & 63;
        sW1t[o * 20 + f] = W1[i];
    }
    for (int i = threadIdx.x; i < 2048; i += 256) sW2[i] = W2[i];
    if (threadIdx.x < 64) sb1[threadIdx.x] = b1[threadIdx.x];
    else if (threadIdx.x >= 64 && threadIdx.x < 96) sb2v[threadIdx.x - 64] = b2[threadIdx.x - 64];
    else if (threadIdx.x >= 96 && threadIdx.x < 128) sW3[threadIdx.x - 96] = W3[threadIdx.x - 96];
    if (threadIdx.x == 128) sb3 = b3[0];
    __syncthreads();

    int e = blockIdx.x * 256 + threadIdx.x;
    const v4* hp = reinterpret_cast<const v4*>(h + (size_t)e * NF);
    v4 v0 = hp[0], v1 = hp[1], v2 = hp[2], v3 = hp[3], v4v = hp[4];

    const v4* b2p = reinterpret_cast<const v4*>(sb2v);
    v4 x20 = b2p[0], x21 = b2p[1], x22 = b2p[2], x23 = b2p[3],
       x24 = b2p[4], x25 = b2p[5], x26 = b2p[6], x27 = b2p[7];
    for (int o = 0; o < 64; o++) {
        float x1 = sb1[o] + dot20v(v0, v1, v2, v3, v4v, (const v4*)&sW1t[o * 20]);
        x1 = selu_f(x1);
        v4 xb = bc4(x1);
        const v4* w = (const v4*)&sW2[o * 32];
        x20 = EWFMA(xb, w[0], x20); x21 = EWFMA(xb, w[1], x21);
        x22 = EWFMA(xb, w[2], x22); x23 = EWFMA(xb, w[3], x23);
        x24 = EWFMA(xb, w[4], x24); x25 = EWFMA(xb, w[5], x25);
        x26 = EWFMA(xb, w[6], x26); x27 = EWFMA(xb, w[7], x27);
    }
    const v4* w3p = reinterpret_cast<const v4*>(sW3);
    v4 accv = selu4(x20) * w3p[0];
    accv = EWFMA(selu4(x21), w3p[1], accv);
    accv = EWFMA(selu4(x22), w3p[2], accv);
    accv = EWFMA(selu4(x23), w3p[3], accv);
    accv = EWFMA(selu4(x24), w3p[4], accv);
    accv = EWFMA(selu4(x25), w3p[5], accv);
    accv = EWFMA(selu4(x26), w3p[6], accv);
    accv = EWFMA(selu4(x27), w3p[7], accv);
    float acc = sb3 + hsum4(accv);
    float sp = fmaxf(acc, 0.f) + log1pf(__expf(-fabsf(acc)));
    float w = sp + 0.1f;
    w = fminf(fmaxf(w, 0.1f), 10.f);
    out[e] = w;
}

extern "C" void kernel_launch(void* const* d_in, const int* in_sizes, int n_in,
                              void* d_out, int out_size, void* d_ws, size_t ws_size,
                              hipStream_t stream) {
    const float* edge_attr = (const float*)d_in[0];
    const float* msg_W1   = (const float*)d_in[1];
    const float* msg_b1   = (const float*)d_in[2];
    const float* msg_W2   = (const float*)d_in[3];
    const float* msg_b2   = (const float*)d_in[4];
    const float* gru_Wih  = (const float*)d_in[5];
    const float* gru_Whh  = (const float*)d_in[6];
    const float* gru_bih  = (const float*)d_in[7];
    const float* gru_bhh  = (const float*)d_in[8];
    const float* ro_W1    = (const float*)d_in[9];
    const float* ro_b1    = (const float*)d_in[10];
    const float* ro_W2    = (const float*)d_in[11];
    const float* ro_b2    = (const float*)d_in[12];
    const float* ro_W3    = (const float*)d_in[13];
    const float* ro_b3    = (const float*)d_in[14];
    const int* edge_index = (const int*)d_in[15];
    const int* dst = edge_index + E_EDGES;   // row 1 of (2,E)

    float*  h_ws = (float*)d_ws;                                  // E*20 f32
    __half* BtA  = (__half*)(h_ws + (size_t)E_EDGES * NF);        // E*32 f16
    __half* BtB  = BtA + (size_t)E_EDGES * 32;                    // E*32 f16 (ping-pong)

    size_t need = (size_t)E_EDGES * NF * sizeof(float)
                + 2 * (size_t)E_EDGES * 32 * sizeof(__half);
    bool fused = ws_size >= need;

    dim3 block(256);
    dim3 gridB(E_EDGES / 256);
    dim3 gridS(E_EDGES * 2 / 256);     // 4 lanes per 2-edge pair

    kernel_B0<<<gridB, block, 0, stream>>>(edge_attr, msg_W1, msg_b1, BtA);

    const float* hin = edge_attr;
    __half* Bin = BtA;
    __half* Bout = BtB;
    for (int s = 0; s < 4; s++) {
        if (!fused && s > 0)
            kernel_B0<<<gridB, block, 0, stream>>>(hin, msg_W1, msg_b1, BtA);
        if (fused && s < 3) {
            kernel_stepT<true><<<gridS, block, 0, stream>>>(hin, h_ws, Bin, dst,
                msg_W1, msg_b1, msg_W2, msg_b2, gru_Wih, gru_Whh, gru_bih, gru_bhh,
                Bout);
            __half* tmp = Bin; Bin = Bout; Bout = tmp;
        } else {
            kernel_stepT<false><<<gridS, block, 0, stream>>>(hin, h_ws, Bin, dst,
                msg_W1, msg_b1, msg_W2, msg_b2, gru_Wih, gru_Whh, gru_bih, gru_bhh,
                nullptr);
        }
        hin = h_ws;
    }
    kernel_readout<<<gridB, block, 0, stream>>>(h_ws, ro_W1, ro_b1, ro_W2, ro_b2,
                                                ro_W3, ro_b3, (float*)d_out);
}